// Round 1
// 473.029 us; speedup vs baseline: 1.0231x; 1.0231x over previous
//
#include <hip/hip_runtime.h>
#include <math.h>

#define D_FEAT 524288        // 512*32*32
#define NSAMP  128
#define NCLS   12
#define BK     256           // K elements staged in LDS per slice
#define KPB    2048          // K per block (8 slices of BK)
#define NB     256           // split-K blocks for the Gram kernel
#define D4     131072        // D_FEAT / 4

typedef __bf16 bf16x8 __attribute__((ext_vector_type(8)));
typedef float  f32x16 __attribute__((ext_vector_type(16)));

__device__ __forceinline__ unsigned pack_bf16(float a, float b) {
  // round-to-nearest-even fp32 -> bf16, packed low/high
  unsigned ua = __float_as_uint(a); ua += 0x7fffu + ((ua >> 16) & 1u);
  unsigned ub = __float_as_uint(b); ub += 0x7fffu + ((ub >> 16) & 1u);
  return (ua >> 16) | (ub & 0xffff0000u);
}

// ---------------------------------------------------------------------------
// Kernel 1: split-K Gram partials, double-buffered LDS (one barrier / slice).
// LDS layout per buffer: 16-byte units; unit(s, g) at g*128 + (s ^ (g&7))
// holds bf16 elements k=8g..8g+7 of sample s (XOR swizzle, conflict-free).
// 8 waves: wave w computes rows Ra=(w>>2)*64 .. +63, cols Ca=(w&3)*32 .. +31.
// Hazard check: slice s reads buf[s&1], writes buf[(s+1)&1]; buf[(s+1)&1] was
// last read in slice s-1, and every wave passed the top-of-slice barrier after
// finishing those reads -> single barrier per slice is sufficient.
// ---------------------------------------------------------------------------
__global__ __launch_bounds__(512, 2) void gram_k(const float* __restrict__ f,
                                                 float* __restrict__ gram,
                                                 float* __restrict__ partial,
                                                 int atomic_mode) {
  __shared__ __align__(16) unsigned char lds[2 * BK * NSAMP * 2];  // 128 KB
  const int t    = threadIdx.x;
  const int b    = blockIdx.x;
  const int wave = t >> 6;
  const int lane = t & 63;
  const int sl   = lane & 31;
  const int hi   = lane >> 5;
  const int Ra   = (wave >> 2) * 64;
  const int Ca   = (wave & 3) * 32;
  const int kq   = lane;            // float4 column within slice (0..63)
  const size_t k0 = (size_t)b * KPB;

  f32x16 acc0, acc1;
#pragma unroll
  for (int i = 0; i < 16; ++i) { acc0[i] = 0.f; acc1[i] = 0.f; }

  const int wg      = kq >> 1;      // staging kgroup
  const int halfsel = kq & 1;

  float4 pf[16];
  // preload + stage slice 0 into buffer 0
#pragma unroll
  for (int i = 0; i < 16; ++i) {
    const int s = i * 8 + wave;
    pf[i] = *(const float4*)(f + (size_t)s * D_FEAT + k0 + kq * 4);
  }
#pragma unroll
  for (int i = 0; i < 16; ++i) {
    const int s = i * 8 + wave;
    uint2 p; p.x = pack_bf16(pf[i].x, pf[i].y); p.y = pack_bf16(pf[i].z, pf[i].w);
    *(uint2*)(lds + (wg * NSAMP + (s ^ (wg & 7))) * 16 + halfsel * 8) = p;
  }

  for (int sli = 0; sli < KPB / BK; ++sli) {
    __syncthreads();  // buf[sli&1] fully staged; buf[(sli+1)&1] fully consumed
    const unsigned char* rb = lds + (sli & 1) * (BK * NSAMP * 2);
    unsigned char*       wb = lds + ((sli + 1) & 1) * (BK * NSAMP * 2);
    if (sli < KPB / BK - 1) {
      const size_t kb = k0 + (size_t)(sli + 1) * BK;
#pragma unroll
      for (int i = 0; i < 16; ++i) {
        const int s = i * 8 + wave;
        pf[i] = *(const float4*)(f + (size_t)s * D_FEAT + kb + kq * 4);
      }
    }
#pragma unroll
    for (int t16 = 0; t16 < 16; ++t16) {
      const int g = 2 * t16 + hi, gx = g & 7;
      const unsigned char* base = rb + g * (NSAMP * 16);
      bf16x8 a0 = *(const bf16x8*)(base + (((Ra      + sl) ^ gx) << 4));
      bf16x8 a1 = *(const bf16x8*)(base + (((Ra + 32 + sl) ^ gx) << 4));
      bf16x8 b0 = *(const bf16x8*)(base + (((Ca      + sl) ^ gx) << 4));
      acc0 = __builtin_amdgcn_mfma_f32_32x32x16_bf16(a0, b0, acc0, 0, 0, 0);
      acc1 = __builtin_amdgcn_mfma_f32_32x32x16_bf16(a1, b0, acc1, 0, 0, 0);
    }
    if (sli < KPB / BK - 1) {
      // write next slice into the other buffer; no barrier needed here
#pragma unroll
      for (int i = 0; i < 16; ++i) {
        const int s = i * 8 + wave;
        uint2 p; p.x = pack_bf16(pf[i].x, pf[i].y); p.y = pack_bf16(pf[i].z, pf[i].w);
        *(uint2*)(wb + (wg * NSAMP + (s ^ (wg & 7))) * 16 + halfsel * 8) = p;
      }
    }
  }

  // epilogue: C/D layout col=lane&31, row=4*(lane>>5)+(reg&3)+8*(reg>>2)
  if (atomic_mode) {
#pragma unroll
    for (int r = 0; r < 16; ++r) {
      const int row0 = Ra + 4 * hi + (r & 3) + 8 * (r >> 2);
      atomicAdd(gram + row0 * NSAMP + Ca + sl, acc0[r]);
      atomicAdd(gram + (row0 + 32) * NSAMP + Ca + sl, acc1[r]);
    }
  } else {
    float* p = partial + (size_t)b * (NSAMP * NSAMP);
#pragma unroll
    for (int r = 0; r < 16; ++r) {
      const int row0 = Ra + 4 * hi + (r & 3) + 8 * (r >> 2);
      p[row0 * NSAMP + Ca + sl]        = acc0[r];
      p[(row0 + 32) * NSAMP + Ca + sl] = acc1[r];
    }
  }
}

// ---------------------------------------------------------------------------
// Kernel 1b: reduce NB partial Grams -> gram[128][128].
// 256 blocks x 64 threads: every CU active, 1 idx per thread, unroll 16.
// ---------------------------------------------------------------------------
__global__ __launch_bounds__(64) void reduce_k(const float* __restrict__ partial,
                                               float* __restrict__ gram) {
  const int idx = blockIdx.x * 64 + threadIdx.x;  // 256 blocks -> 16384
  float s = 0.f;
#pragma unroll 16
  for (int b = 0; b < NB; ++b) s += partial[(size_t)b * (NSAMP * NSAMP) + idx];
  gram[idx] = s;
}

// ---------------------------------------------------------------------------
// Kernel 2: weights + class-sorted sample order (1 block, 256 threads).
// Gram (64 KB) staged into LDS with one coalesced load; all row scans hit LDS.
// ---------------------------------------------------------------------------
__global__ __launch_bounds__(256) void weights_k(const float* __restrict__ gram,
                          const int* __restrict__ labels,
                          float* __restrict__ w_out, int* __restrict__ order_out,
                          int* __restrict__ off_out) {
  __shared__ __align__(16) float g[NSAMP * NSAMP];  // 64 KB
  __shared__ int   lab[NSAMP];
  __shared__ float wv[NSAMP];
  __shared__ float wsum_s;
  __shared__ int   cnt[NCLS];
  __shared__ int   off[NCLS + 1];
  const int t = threadIdx.x;

  // cooperative coalesced load: 256 threads x 16 float4 = 16384 floats
  {
    float4* g4 = (float4*)g;
    const float4* s4 = (const float4*)gram;
#pragma unroll
    for (int i = 0; i < 16; ++i) g4[i * 256 + t] = s4[i * 256 + t];
  }
  if (t < NSAMP) lab[t] = labels[t];
  if (t < NCLS)  cnt[t] = 0;
  __syncthreads();

  if (t < NSAMP) {
    const int   myl = lab[t];
    const float st  = g[t * NSAMP + t];
    float dsum = 0.f;
    for (int j = 0; j < NSAMP; ++j) {
      if (j != t && lab[j] == myl) {
        float d2 = st + g[j * NSAMP + j] - 2.f * g[t * NSAMP + j];
        if (d2 > 0.f) dsum += sqrtf(d2);
      }
    }
    wv[t] = 1.f / (sqrtf(dsum * dsum + 25.f) + 1e-12f);
    atomicAdd(&cnt[myl], 1);
  }
  __syncthreads();

  if (t < 64) {  // wave 0: parallel normalization sum over 128 weights
    float s = wv[t] + wv[t + 64];
#pragma unroll
    for (int o = 32; o > 0; o >>= 1) s += __shfl_down(s, o);
    if (t == 0) {
      wsum_s = s;
      off[0] = 0;
      for (int c = 0; c < NCLS; ++c) off[c + 1] = off[c] + cnt[c];
    }
  }
  __syncthreads();

  if (t < NSAMP) {
    const int myl = lab[t];
    int rank = 0;
    for (int j = 0; j < t; ++j) rank += (lab[j] == myl) ? 1 : 0;
    const int pos  = off[myl] + rank;
    order_out[pos] = t;
    w_out[pos]     = wv[t] / (wsum_s + 1e-12f);
  }
  if (t <= NCLS) off_out[t] = off[t];
}

// ---------------------------------------------------------------------------
// Kernel 3: weighted class scatter-sum. One float4 column per thread,
// samples iterated in class-sorted order (uniform control flow, no dynamic
// accumulator indexing). Second full read of features. (Unchanged: modeled
// HBM-BW-bound; isolating this round's deltas to gram/reduce/weights.)
// ---------------------------------------------------------------------------
__global__ __launch_bounds__(256) void scatter_k(const float* __restrict__ f,
                                                 const float* __restrict__ w,
                                                 const int* __restrict__ order,
                                                 const int* __restrict__ off,
                                                 float* __restrict__ out) {
  __shared__ float w_l[NSAMP];
  __shared__ int   ord_l[NSAMP];
  __shared__ int   off_l[NCLS + 1];
  const int t = threadIdx.x;
  if (t < NSAMP) { w_l[t] = w[t]; ord_l[t] = order[t]; }
  if (t <= NCLS) off_l[t] = off[t];
  __syncthreads();
  const size_t d4 = (size_t)blockIdx.x * 256 + t;
  const float4* f4 = (const float4*)f;
  float4* o4 = (float4*)out;
  for (int c = 0; c < NCLS; ++c) {
    float4 acc = make_float4(0.f, 0.f, 0.f, 0.f);
    const int e = off_l[c + 1];
#pragma unroll 4
    for (int j = off_l[c]; j < e; ++j) {
      const float  wj = w_l[j];
      const float4 v  = f4[(size_t)ord_l[j] * D4 + d4];
      acc.x += wj * v.x; acc.y += wj * v.y; acc.z += wj * v.z; acc.w += wj * v.w;
    }
    o4[(size_t)c * D4 + d4] = acc;
  }
}

extern "C" void kernel_launch(void* const* d_in, const int* in_sizes, int n_in,
                              void* d_out, int out_size, void* d_ws, size_t ws_size,
                              hipStream_t stream) {
  const float* f      = (const float*)d_in[0];
  const int*   labels = (const int*)d_in[1];
  float* out  = (float*)d_out;
  float* ws_f = (float*)d_ws;

  // ws layout (floats): [0,16384) gram | [16384,16512) w_sorted |
  // [16512,16640) order(int) | [16640,16656) cls_off(int) | [32768,...) partials
  float* gram     = ws_f;
  float* w_sorted = ws_f + 16384;
  int*   order    = (int*)(ws_f + 16384 + 128);
  int*   clsoff   = (int*)(ws_f + 16384 + 256);
  float* partial  = ws_f + 32768;

  const size_t need = (size_t)32768 * 4 + (size_t)NB * NSAMP * NSAMP * 4;  // ~16.9 MB
  const int atomic_mode = (ws_size < need) ? 1 : 0;

  if (atomic_mode) hipMemsetAsync(gram, 0, NSAMP * NSAMP * sizeof(float), stream);
  gram_k<<<NB, 512, 0, stream>>>(f, gram, partial, atomic_mode);
  if (!atomic_mode) reduce_k<<<256, 64, 0, stream>>>(partial, gram);
  weights_k<<<1, 256, 0, stream>>>(gram, labels, w_sorted, order, clsoff);
  scatter_k<<<D4 / 256, 256, 0, stream>>>(f, w_sorted, order, clsoff, out);
}

// Round 2
// 470.232 us; speedup vs baseline: 1.0291x; 1.0059x over previous
//
#include <hip/hip_runtime.h>
#include <math.h>

#define D_FEAT 524288        // 512*32*32
#define NSAMP  128
#define NCLS   12
#define BK     256           // K elements staged in LDS per slice
#define KPB    2048          // K per block (8 slices of BK)
#define NB     256           // split-K blocks for the Gram kernel
#define D4     131072        // D_FEAT / 4

typedef __bf16 bf16x8 __attribute__((ext_vector_type(8)));
typedef float  f32x16 __attribute__((ext_vector_type(16)));

__device__ __forceinline__ unsigned pack_bf16(float a, float b) {
  // round-to-nearest-even fp32 -> bf16, packed low/high
  unsigned ua = __float_as_uint(a); ua += 0x7fffu + ((ua >> 16) & 1u);
  unsigned ub = __float_as_uint(b); ub += 0x7fffu + ((ub >> 16) & 1u);
  return (ua >> 16) | (ub & 0xffff0000u);
}

// ---------------------------------------------------------------------------
// Kernel 1: split-K Gram partials, double-buffered LDS (one barrier / slice).
// LDS layout per buffer: 16-byte units; unit(s, g) at g*128 + (s ^ (g&7))
// holds bf16 elements k=8g..8g+7 of sample s (XOR swizzle, conflict-free).
// 8 waves: wave w computes rows Ra=(w>>2)*64 .. +63, cols Ca=(w&3)*32 .. +31.
// Hazard check: slice s reads buf[s&1], writes buf[(s+1)&1]; buf[(s+1)&1] was
// last read in slice s-1, and every wave passed the top-of-slice barrier after
// finishing those reads -> single barrier per slice is sufficient.
// ---------------------------------------------------------------------------
__global__ __launch_bounds__(512, 2) void gram_k(const float* __restrict__ f,
                                                 float* __restrict__ gram,
                                                 float* __restrict__ partial,
                                                 int atomic_mode) {
  __shared__ __align__(16) unsigned char lds[2 * BK * NSAMP * 2];  // 128 KB
  const int t    = threadIdx.x;
  const int b    = blockIdx.x;
  const int wave = t >> 6;
  const int lane = t & 63;
  const int sl   = lane & 31;
  const int hi   = lane >> 5;
  const int Ra   = (wave >> 2) * 64;
  const int Ca   = (wave & 3) * 32;
  const int kq   = lane;            // float4 column within slice (0..63)
  const size_t k0 = (size_t)b * KPB;

  f32x16 acc0, acc1;
#pragma unroll
  for (int i = 0; i < 16; ++i) { acc0[i] = 0.f; acc1[i] = 0.f; }

  const int wg      = kq >> 1;      // staging kgroup
  const int halfsel = kq & 1;

  float4 pf[16];
  // preload + stage slice 0 into buffer 0
#pragma unroll
  for (int i = 0; i < 16; ++i) {
    const int s = i * 8 + wave;
    pf[i] = *(const float4*)(f + (size_t)s * D_FEAT + k0 + kq * 4);
  }
#pragma unroll
  for (int i = 0; i < 16; ++i) {
    const int s = i * 8 + wave;
    uint2 p; p.x = pack_bf16(pf[i].x, pf[i].y); p.y = pack_bf16(pf[i].z, pf[i].w);
    *(uint2*)(lds + (wg * NSAMP + (s ^ (wg & 7))) * 16 + halfsel * 8) = p;
  }

  for (int sli = 0; sli < KPB / BK; ++sli) {
    __syncthreads();  // buf[sli&1] fully staged; buf[(sli+1)&1] fully consumed
    const unsigned char* rb = lds + (sli & 1) * (BK * NSAMP * 2);
    unsigned char*       wb = lds + ((sli + 1) & 1) * (BK * NSAMP * 2);
    if (sli < KPB / BK - 1) {
      const size_t kb = k0 + (size_t)(sli + 1) * BK;
#pragma unroll
      for (int i = 0; i < 16; ++i) {
        const int s = i * 8 + wave;
        pf[i] = *(const float4*)(f + (size_t)s * D_FEAT + kb + kq * 4);
      }
    }
#pragma unroll
    for (int t16 = 0; t16 < 16; ++t16) {
      const int g = 2 * t16 + hi, gx = g & 7;
      const unsigned char* base = rb + g * (NSAMP * 16);
      bf16x8 a0 = *(const bf16x8*)(base + (((Ra      + sl) ^ gx) << 4));
      bf16x8 a1 = *(const bf16x8*)(base + (((Ra + 32 + sl) ^ gx) << 4));
      bf16x8 b0 = *(const bf16x8*)(base + (((Ca      + sl) ^ gx) << 4));
      acc0 = __builtin_amdgcn_mfma_f32_32x32x16_bf16(a0, b0, acc0, 0, 0, 0);
      acc1 = __builtin_amdgcn_mfma_f32_32x32x16_bf16(a1, b0, acc1, 0, 0, 0);
    }
    if (sli < KPB / BK - 1) {
      // write next slice into the other buffer; no barrier needed here
#pragma unroll
      for (int i = 0; i < 16; ++i) {
        const int s = i * 8 + wave;
        uint2 p; p.x = pack_bf16(pf[i].x, pf[i].y); p.y = pack_bf16(pf[i].z, pf[i].w);
        *(uint2*)(wb + (wg * NSAMP + (s ^ (wg & 7))) * 16 + halfsel * 8) = p;
      }
    }
  }

  // epilogue: C/D layout col=lane&31, row=4*(lane>>5)+(reg&3)+8*(reg>>2)
  if (atomic_mode) {
#pragma unroll
    for (int r = 0; r < 16; ++r) {
      const int row0 = Ra + 4 * hi + (r & 3) + 8 * (r >> 2);
      atomicAdd(gram + row0 * NSAMP + Ca + sl, acc0[r]);
      atomicAdd(gram + (row0 + 32) * NSAMP + Ca + sl, acc1[r]);
    }
  } else {
    float* p = partial + (size_t)b * (NSAMP * NSAMP);
#pragma unroll
    for (int r = 0; r < 16; ++r) {
      const int row0 = Ra + 4 * hi + (r & 3) + 8 * (r >> 2);
      p[row0 * NSAMP + Ca + sl]        = acc0[r];
      p[(row0 + 32) * NSAMP + Ca + sl] = acc1[r];
    }
  }
}

// ---------------------------------------------------------------------------
// Kernel 1b: reduce NB partial Grams -> gram[128][128].
// 256 blocks x 64 threads; unroll 32 for deeper MLP on the strided loads.
// ---------------------------------------------------------------------------
__global__ __launch_bounds__(64) void reduce_k(const float* __restrict__ partial,
                                               float* __restrict__ gram) {
  const int idx = blockIdx.x * 64 + threadIdx.x;  // 256 blocks -> 16384
  float s = 0.f;
#pragma unroll 32
  for (int b = 0; b < NB; ++b) s += partial[(size_t)b * (NSAMP * NSAMP) + idx];
  gram[idx] = s;
}

// ---------------------------------------------------------------------------
// Kernel 2: weights + class-sorted sample order (1 block, 256 threads).
// Gram (64 KB) staged into LDS with one coalesced load; all row scans hit LDS.
// ---------------------------------------------------------------------------
__global__ __launch_bounds__(256) void weights_k(const float* __restrict__ gram,
                          const int* __restrict__ labels,
                          float* __restrict__ w_out, int* __restrict__ order_out,
                          int* __restrict__ off_out) {
  __shared__ __align__(16) float g[NSAMP * NSAMP];  // 64 KB
  __shared__ int   lab[NSAMP];
  __shared__ float wv[NSAMP];
  __shared__ float wsum_s;
  __shared__ int   cnt[NCLS];
  __shared__ int   off[NCLS + 1];
  const int t = threadIdx.x;

  // cooperative coalesced load: 256 threads x 16 float4 = 16384 floats
  {
    float4* g4 = (float4*)g;
    const float4* s4 = (const float4*)gram;
#pragma unroll
    for (int i = 0; i < 16; ++i) g4[i * 256 + t] = s4[i * 256 + t];
  }
  if (t < NSAMP) lab[t] = labels[t];
  if (t < NCLS)  cnt[t] = 0;
  __syncthreads();

  if (t < NSAMP) {
    const int   myl = lab[t];
    const float st  = g[t * NSAMP + t];
    float dsum = 0.f;
    for (int j = 0; j < NSAMP; ++j) {
      if (j != t && lab[j] == myl) {
        float d2 = st + g[j * NSAMP + j] - 2.f * g[t * NSAMP + j];
        if (d2 > 0.f) dsum += sqrtf(d2);
      }
    }
    wv[t] = 1.f / (sqrtf(dsum * dsum + 25.f) + 1e-12f);
    atomicAdd(&cnt[myl], 1);
  }
  __syncthreads();

  if (t < 64) {  // wave 0: parallel normalization sum over 128 weights
    float s = wv[t] + wv[t + 64];
#pragma unroll
    for (int o = 32; o > 0; o >>= 1) s += __shfl_down(s, o);
    if (t == 0) {
      wsum_s = s;
      off[0] = 0;
      for (int c = 0; c < NCLS; ++c) off[c + 1] = off[c] + cnt[c];
    }
  }
  __syncthreads();

  if (t < NSAMP) {
    const int myl = lab[t];
    int rank = 0;
    for (int j = 0; j < t; ++j) rank += (lab[j] == myl) ? 1 : 0;
    const int pos  = off[myl] + rank;
    order_out[pos] = t;
    w_out[pos]     = wv[t] / (wsum_s + 1e-12f);
  }
  if (t <= NCLS) off_out[t] = off[t];
}

// ---------------------------------------------------------------------------
// Kernel 3: weighted class scatter-sum, v2 — flat class-sorted sample loop.
// One float4 column per thread. Software-pipelined: 8-wide register tile
// double-buffer (cur/nxt, constant-indexed after unroll -> stays in VGPRs),
// so 8-16 independent 16B loads are in flight per thread at all times.
// Class boundaries emit the accumulator via a block-uniform branch (emit[j]).
// ---------------------------------------------------------------------------
__global__ __launch_bounds__(256) void scatter_k(const float* __restrict__ f,
                                                 const float* __restrict__ w,
                                                 const int* __restrict__ order,
                                                 const int* __restrict__ off,
                                                 float* __restrict__ out) {
  __shared__ float w_l[NSAMP];
  __shared__ int   ord_l[NSAMP];
  __shared__ int   emit_l[NSAMP];   // class id if j is last sample of its class, else -1
  __shared__ int   off_l[NCLS + 1];
  const int t = threadIdx.x;
  if (t < NSAMP) { w_l[t] = w[t]; ord_l[t] = order[t]; }
  if (t <= NCLS) off_l[t] = off[t];
  __syncthreads();
  if (t < NSAMP) {
    int e = -1;
#pragma unroll
    for (int c = 0; c < NCLS; ++c)
      if (off_l[c] <= t && off_l[c + 1] == t + 1) e = c;
    emit_l[t] = e;
  }
  __syncthreads();

  const size_t d4 = (size_t)blockIdx.x * 256 + t;
  const float4* f4 = (const float4*)f;
  float4* o4 = (float4*)out;

  float4 cur[8], nxt[8];
  float4 acc = make_float4(0.f, 0.f, 0.f, 0.f);
#pragma unroll
  for (int i = 0; i < 8; ++i) cur[i] = f4[(size_t)ord_l[i] * D4 + d4];

  for (int jb = 0; jb < NSAMP; jb += 8) {
    if (jb + 8 < NSAMP) {
#pragma unroll
      for (int i = 0; i < 8; ++i) nxt[i] = f4[(size_t)ord_l[jb + 8 + i] * D4 + d4];
    }
#pragma unroll
    for (int i = 0; i < 8; ++i) {
      const int j  = jb + i;
      const float wj = w_l[j];
      acc.x += wj * cur[i].x; acc.y += wj * cur[i].y;
      acc.z += wj * cur[i].z; acc.w += wj * cur[i].w;
      const int e = emit_l[j];          // block-uniform
      if (e >= 0) {
        o4[(size_t)e * D4 + d4] = acc;
        acc = make_float4(0.f, 0.f, 0.f, 0.f);
      }
    }
    if (jb + 8 < NSAMP) {
#pragma unroll
      for (int i = 0; i < 8; ++i) cur[i] = nxt[i];
    }
  }
  // empty classes: segment_sum semantics -> zero output
#pragma unroll
  for (int c = 0; c < NCLS; ++c)
    if (off_l[c + 1] == off_l[c]) o4[(size_t)c * D4 + d4] = make_float4(0.f, 0.f, 0.f, 0.f);
}

extern "C" void kernel_launch(void* const* d_in, const int* in_sizes, int n_in,
                              void* d_out, int out_size, void* d_ws, size_t ws_size,
                              hipStream_t stream) {
  const float* f      = (const float*)d_in[0];
  const int*   labels = (const int*)d_in[1];
  float* out  = (float*)d_out;
  float* ws_f = (float*)d_ws;

  // ws layout (floats): [0,16384) gram | [16384,16512) w_sorted |
  // [16512,16640) order(int) | [16640,16656) cls_off(int) | [32768,...) partials
  float* gram     = ws_f;
  float* w_sorted = ws_f + 16384;
  int*   order    = (int*)(ws_f + 16384 + 128);
  int*   clsoff   = (int*)(ws_f + 16384 + 256);
  float* partial  = ws_f + 32768;

  const size_t need = (size_t)32768 * 4 + (size_t)NB * NSAMP * NSAMP * 4;  // ~16.9 MB
  const int atomic_mode = (ws_size < need) ? 1 : 0;

  if (atomic_mode) hipMemsetAsync(gram, 0, NSAMP * NSAMP * sizeof(float), stream);
  gram_k<<<NB, 512, 0, stream>>>(f, gram, partial, atomic_mode);
  if (!atomic_mode) reduce_k<<<256, 64, 0, stream>>>(partial, gram);
  weights_k<<<1, 256, 0, stream>>>(gram, labels, w_sorted, order, clsoff);
  scatter_k<<<D4 / 256, 256, 0, stream>>>(f, w_sorted, order, clsoff, out);
}